// Round 1
// baseline (871.062 us; speedup 1.0000x reference)
//
#include <hip/hip_runtime.h>

// LinearAttention on MI355X (gfx950), bf16 MFMA pipeline.
// out = z ∘ (q @ (kᵀv @ W_outᵀ)) + b_out,  z = 1/(q·ksum + eps)
// All GEMMs: C = A·Bᵀ, m97-style 128x128 tile, BK=32, global_load_lds(16B).

#define EPS 1e-6f

using u16 = unsigned short;
typedef __attribute__((ext_vector_type(4))) float f32x4;
typedef __attribute__((ext_vector_type(8))) __bf16 bf16x8;

__device__ __forceinline__ u16 f2b(float f) {
  unsigned u = __builtin_bit_cast(unsigned, f);
  u += 0x7FFFu + ((u >> 16) & 1u);     // RNE
  return (u16)(u >> 16);
}
__device__ __forceinline__ float b2f(u16 h) {
  return __builtin_bit_cast(float, (unsigned)h << 16);
}

typedef const __attribute__((address_space(1))) void* gas1_t;
typedef __attribute__((address_space(3))) void* las3_t;

__device__ __forceinline__ void load16_to_lds(const void* g, void* l) {
  // LDS dest is wave-uniform base + lane*16 (measured m104/m108) — l must be
  // wave-uniform; per-lane global addr in g.
  __builtin_amdgcn_global_load_lds((gas1_t)g, (las3_t)l, 16, 0, 0);
}

// ---------------------------------------------------------------------------
// C = A * B^T.  A: [M][K] bf16 (lda), B: [N][K] bf16 (ldb). Batched via z-dim.
// MODE 0: bf16 out, relu+eps applied to cols < 2048 (qkv epilogue)
// MODE 1: bf16 out, plain (kv / kvw^T)
// MODE 2: f32 out, v*z[row] + bias[col]  (final output)
// ---------------------------------------------------------------------------
template<int MODE>
__global__ __launch_bounds__(256) void gemm_abT(
    const u16* __restrict__ A, const u16* __restrict__ B, void* __restrict__ Cv,
    int M, int N, int K, int lda, int ldb, int ldc,
    long long sA, long long sB, long long sC,
    const float* __restrict__ zvec, const float* __restrict__ bias)
{
  __shared__ u16 lA[128 * 32];
  __shared__ u16 lB[128 * 32];
  const int tid  = threadIdx.x;
  const int wave = tid >> 6, lane = tid & 63;
  const int bm = blockIdx.x, bn = blockIdx.y, bz = blockIdx.z;
  const u16* Ab = A + (long long)bz * sA;
  const u16* Bb = B + (long long)bz * sB;

  // staging: 512 chunks of 16B per tile; chunk c -> row c>>2, 16B-seg c&3
  const int c0 = wave * 64 + lane;
  const int c1 = 256 + c0;
  const u16* gA0 = Ab + (long long)(bm * 128 + (c0 >> 2)) * lda + (c0 & 3) * 8;
  const u16* gA1 = Ab + (long long)(bm * 128 + (c1 >> 2)) * lda + (c1 & 3) * 8;
  const u16* gB0 = Bb + (long long)(bn * 128 + (c0 >> 2)) * ldb + (c0 & 3) * 8;
  const u16* gB1 = Bb + (long long)(bn * 128 + (c1 >> 2)) * ldb + (c1 & 3) * 8;
  u16* lA0 = &lA[(wave * 64) * 8];         // wave-uniform LDS bases
  u16* lA1 = &lA[(256 + wave * 64) * 8];
  u16* lB0 = &lB[(wave * 64) * 8];
  u16* lB1 = &lB[(256 + wave * 64) * 8];

  // wave -> 64x64 subtile; MFMA A/B frag: row = lane&15, k = (lane>>4)*8..+7
  const int wm = (wave & 1) * 64, wn = (wave >> 1) * 64;
  const int aoff = (wm + (lane & 15)) * 32 + (lane >> 4) * 8;
  const int boff = (wn + (lane & 15)) * 32 + (lane >> 4) * 8;

  f32x4 acc[4][4];
  #pragma unroll
  for (int i = 0; i < 4; i++)
    #pragma unroll
    for (int j = 0; j < 4; j++) acc[i][j] = f32x4{0.f, 0.f, 0.f, 0.f};

  for (int k0 = 0; k0 < K; k0 += 32) {
    load16_to_lds(gA0 + k0, lA0);
    load16_to_lds(gA1 + k0, lA1);
    load16_to_lds(gB0 + k0, lB0);
    load16_to_lds(gB1 + k0, lB1);
    __syncthreads();                       // vmcnt(0) drain + barrier
    bf16x8 af[4], bfv[4];
    #pragma unroll
    for (int i = 0; i < 4; i++) af[i]  = *(const bf16x8*)&lA[aoff + i * 16 * 32];
    #pragma unroll
    for (int j = 0; j < 4; j++) bfv[j] = *(const bf16x8*)&lB[boff + j * 16 * 32];
    #pragma unroll
    for (int i = 0; i < 4; i++)
      #pragma unroll
      for (int j = 0; j < 4; j++)
        acc[i][j] = __builtin_amdgcn_mfma_f32_16x16x32_bf16(af[i], bfv[j], acc[i][j], 0, 0, 0);
    __syncthreads();                       // LDS reads done before next stage
  }

  // C/D layout (m89-verified): col = lane&15, row = (lane>>4)*4 + reg
  const int quad = lane >> 4, lc = lane & 15;
  const int rowb = bm * 128 + wm + quad * 4;
  const int colb = bn * 128 + wn + lc;
  #pragma unroll
  for (int i = 0; i < 4; i++) {
    #pragma unroll
    for (int j = 0; j < 4; j++) {
      const int col = colb + j * 16;
      float bj = 0.f;
      if (MODE == 2) bj = bias[col];
      #pragma unroll
      for (int r = 0; r < 4; r++) {
        const int row = rowb + i * 16 + r;
        float v = acc[i][j][r];
        if (MODE == 0) {
          if (col < 2048) v = fmaxf(v, 0.f) + EPS;   // relu+eps on q,k only
          ((u16*)Cv + (long long)bz * sC)[(long long)row * ldc + col] = f2b(v);
        } else if (MODE == 1) {
          ((u16*)Cv + (long long)bz * sC)[(long long)row * ldc + col] = f2b(v);
        } else {
          float zz = zvec[(long long)bz * M + row];
          ((float*)Cv + (long long)bz * sC)[(long long)row * ldc + col] = v * zz + bj;
        }
      }
    }
  }
}

// fp32 -> bf16 bulk convert (vectorized, grid-stride)
__global__ void cvt_f32_bf16(const float* __restrict__ s, u16* __restrict__ d, int n4) {
  int i = blockIdx.x * blockDim.x + threadIdx.x;
  int st = gridDim.x * blockDim.x;
  for (; i < n4; i += st) {
    float4 f = ((const float4*)s)[i];
    uint2 o;
    o.x = (unsigned)f2b(f.x) | ((unsigned)f2b(f.y) << 16);
    o.y = (unsigned)f2b(f.z) | ((unsigned)f2b(f.w) << 16);
    ((uint2*)d)[i] = o;
  }
}

// Transpose k,v parts of qkv[32768][3072] into kT/vT [b][1024][4096]
__global__ void transpose_kv(const u16* __restrict__ qkv,
                             u16* __restrict__ kT, u16* __restrict__ vT) {
  __shared__ u16 tile[64][72];             // +8 pad: transposed reads spread banks
  const int b = blockIdx.z >> 1, which = blockIdx.z & 1;
  const int n0 = blockIdx.x * 64, d0 = blockIdx.y * 64;
  const u16* src = qkv + (long long)b * 4096 * 3072 + 1024 + which * 1024;
  u16* dst = (which ? vT : kT) + (long long)b * 1024 * 4096;
  const int t = threadIdx.x;
  #pragma unroll
  for (int c = t; c < 512; c += 256) {
    int r = c >> 3, sg = c & 7;
    uint4 dd = *(const uint4*)(src + (long long)(n0 + r) * 3072 + d0 + sg * 8);
    *(uint4*)&tile[r][sg * 8] = dd;
  }
  __syncthreads();
  #pragma unroll
  for (int c = t; c < 512; c += 256) {
    int dr = c >> 3, sg = c & 7;
    union { u16 h[8]; uint4 v; } tmp;
    #pragma unroll
    for (int u = 0; u < 8; u++) tmp.h[u] = tile[sg * 8 + u][dr];
    *(uint4*)(dst + (long long)(d0 + dr) * 4096 + n0 + sg * 8) = tmp.v;
  }
}

// ksum[b*1024+d] = sum_n kT[b][d][n]; one wave per row (rows contiguous in n)
__global__ void ksum_kernel(const u16* __restrict__ kT, float* __restrict__ ksum) {
  const int row  = blockIdx.x * 4 + (threadIdx.x >> 6);
  const int lane = threadIdx.x & 63;
  const uint4* p = (const uint4*)(kT + (long long)row * 4096);
  float s = 0.f;
  #pragma unroll
  for (int c = 0; c < 8; c++) {
    uint4 d = p[lane + c * 64];
    unsigned w[4] = {d.x, d.y, d.z, d.w};
    #pragma unroll
    for (int q = 0; q < 4; q++)
      s += b2f((u16)(w[q] & 0xFFFF)) + b2f((u16)(w[q] >> 16));
  }
  #pragma unroll
  for (int o = 32; o > 0; o >>= 1) s += __shfl_down(s, o);
  if (lane == 0) ksum[row] = s;
}

// z[row] = 1/(q[row,:]·ksum[b,:] + eps); one wave per row
__global__ void z_kernel(const u16* __restrict__ qkv, const float* __restrict__ ksum,
                         float* __restrict__ z) {
  const int row  = blockIdx.x * 4 + (threadIdx.x >> 6);   // 0..32767
  const int lane = threadIdx.x & 63;
  const int b = row >> 12;
  const uint4* q = (const uint4*)(qkv + (long long)row * 3072);  // q = cols 0..1023
  const float* ks = ksum + b * 1024;
  float s = 0.f;
  #pragma unroll
  for (int c = 0; c < 2; c++) {
    int idx = lane + c * 64;
    uint4 d = q[idx];
    unsigned w[4] = {d.x, d.y, d.z, d.w};
    const float* kk = ks + idx * 8;
    #pragma unroll
    for (int qq = 0; qq < 4; qq++)
      s += b2f((u16)(w[qq] & 0xFFFF)) * kk[qq * 2]
         + b2f((u16)(w[qq] >> 16))    * kk[qq * 2 + 1];
  }
  #pragma unroll
  for (int o = 32; o > 0; o >>= 1) s += __shfl_down(s, o);
  if (lane == 0) z[row] = 1.0f / (s + EPS);
}

extern "C" void kernel_launch(void* const* d_in, const int* in_sizes, int n_in,
                              void* d_out, int out_size, void* d_ws, size_t ws_size,
                              hipStream_t stream) {
  const float* x    = (const float*)d_in[0];   // [8,4096,1024]
  const float* Wqkv = (const float*)d_in[1];   // [3072,1024]
  const float* Wout = (const float*)d_in[2];   // [1024,1024]
  const float* bout = (const float*)d_in[3];   // [1024]

  char* ws = (char*)d_ws;                      // needs ~360.2 MiB
  u16* x_bf    = (u16*)(ws + 0);               // 64 MiB (dead after GEMM1)
  u16* kT      = (u16*)(ws + 0);               // reuses x_bf region, 64 MiB
  u16* wqkv_bf = (u16*)(ws + 67108864);        // 6 MiB
  u16* wout_bf = (u16*)(ws + 73400320);        // 2 MiB
  u16* qkv     = (u16*)(ws + 75497472);        // 192 MiB
  u16* vT      = (u16*)(ws + 276824064);       // 64 MiB
  u16* kv      = (u16*)(ws + 343932928);       // 16 MiB
  u16* kvwT    = (u16*)(ws + 360710144);       // 16 MiB
  float* ksum  = (float*)(ws + 377487360);     // 32 KiB
  float* z     = (float*)(ws + 377520128);     // 128 KiB

  // fp32 -> bf16
  cvt_f32_bf16<<<4096, 256, 0, stream>>>(x,    x_bf,    33554432 / 4);
  cvt_f32_bf16<<<1024, 256, 0, stream>>>(Wqkv, wqkv_bf,  3145728 / 4);
  cvt_f32_bf16<<<512,  256, 0, stream>>>(Wout, wout_bf,  1048576 / 4);

  // GEMM1: qkv[n][f] = x @ Wqkv^T, relu+eps on f<2048, bf16 out
  gemm_abT<0><<<dim3(256, 24, 1), 256, 0, stream>>>(
      x_bf, wqkv_bf, qkv, 32768, 3072, 1024, 1024, 1024, 3072,
      0, 0, 0, nullptr, nullptr);

  // kT/vT [b][d][n] + ksum + z
  transpose_kv<<<dim3(64, 16, 16), 256, 0, stream>>>(qkv, kT, vT);
  ksum_kernel<<<2048, 256, 0, stream>>>(kT, ksum);
  z_kernel<<<8192, 256, 0, stream>>>(qkv, ksum, z);

  // GEMM2 (batched 8): kv[d][e] = kT_b @ vT_b^T  (K=4096)
  gemm_abT<1><<<dim3(8, 8, 8), 256, 0, stream>>>(
      kT, vT, kv, 1024, 1024, 4096, 4096, 4096, 1024,
      4194304, 4194304, 1048576, nullptr, nullptr);

  // GEMM2b (batched 8): kvwT[f][d] = Wout @ kv_b^T  (K=1024)
  gemm_abT<1><<<dim3(8, 8, 8), 256, 0, stream>>>(
      wout_bf, kv, kvwT, 1024, 1024, 1024, 1024, 1024, 1024,
      0, 1048576, 1048576, nullptr, nullptr);

  // GEMM3 (batched 8): out[n][f] = z[n] * (q_b @ kvwT_b^T) + b_out[f], fp32
  gemm_abT<2><<<dim3(32, 8, 8), 256, 0, stream>>>(
      qkv, kvwT, d_out, 4096, 1024, 1024, 3072, 1024, 1024,
      12582912, 1048576, 4194304, z, bout);
}

// Round 2
// 792.136 us; speedup vs baseline: 1.0996x; 1.0996x over previous
//
#include <hip/hip_runtime.h>

// LinearAttention on MI355X (gfx950), bf16 MFMA pipeline.
// out = z ∘ (q @ (kᵀv @ W_outᵀ)) + b_out,  z = 1/(q·ksum + eps)
// R2: XCD-aware block swizzle (M striped by 8 so each A-tile is owned by one
// XCD, L2-resident); GEMM1 epilogue writes q n-major + k/v TRANSPOSED (kT/vT)
// + fused ksum atomics — transpose_kv and ksum kernels eliminated.

#define EPS 1e-6f

using u16 = unsigned short;
typedef __attribute__((ext_vector_type(4))) float f32x4;
typedef __attribute__((ext_vector_type(8))) __bf16 bf16x8;

__device__ __forceinline__ u16 f2b(float f) {
  unsigned u = __builtin_bit_cast(unsigned, f);
  u += 0x7FFFu + ((u >> 16) & 1u);     // RNE
  return (u16)(u >> 16);
}
__device__ __forceinline__ float b2f(u16 h) {
  return __builtin_bit_cast(float, (unsigned)h << 16);
}

typedef const __attribute__((address_space(1))) void* gas1_t;
typedef __attribute__((address_space(3))) void* las3_t;

__device__ __forceinline__ void load16_to_lds(const void* g, void* l) {
  __builtin_amdgcn_global_load_lds((gas1_t)g, (las3_t)l, 16, 0, 0);
}

// ---------------------------------------------------------------------------
// C = A * B^T.  A: [M][K] bf16 (lda), B: [N][K] bf16 (ldb). Batched via z-dim.
// MODE 0: GEMM1 fused epilogue — q (relu+eps, n-major) / kT (relu+eps,
//         transposed, +ksum atomics) / vT (transposed). ldc = q leading dim.
// MODE 1: bf16 out, plain
// MODE 2: f32 out, v*z[row] + bias[col]
// Requires gridDim.x (M-tiles) % 8 == 0 for the XCD swizzle.
// ---------------------------------------------------------------------------
template<int MODE>
__global__ __launch_bounds__(256) void gemm_abT(
    const u16* __restrict__ A, const u16* __restrict__ B, void* __restrict__ Cv,
    int M, int N, int K, int lda, int ldb, int ldc,
    long long sA, long long sB, long long sC,
    const float* __restrict__ zvec, const float* __restrict__ bias,
    u16* __restrict__ kT, u16* __restrict__ vT, float* __restrict__ ksum)
{
  __shared__ u16 lA[128 * 32];
  __shared__ u16 lB[128 * 32];
  const int tid  = threadIdx.x;
  const int wave = tid >> 6, lane = tid & 63;
  const int TN = gridDim.y;
  // XCD-aware swizzle: lin%8 ~ XCD (round-robin dispatch heuristic).
  // XCD c owns M-tiles {c, c+8, ...}; within an XCD, N varies fastest →
  // the 128x128 A-tile (256 KB) stays resident in that XCD's 4 MB L2.
  const int lin = blockIdx.x + gridDim.x * blockIdx.y;
  const int xcd = lin & 7, g = lin >> 3;
  const int bm = (g / TN) * 8 + xcd;
  const int bn = g % TN;
  const int bz = blockIdx.z;
  const u16* Ab = A + (long long)bz * sA;
  const u16* Bb = B + (long long)bz * sB;

  // staging: 512 chunks of 16B per tile; chunk c -> row c>>2, 16B-seg c&3
  const int c0 = wave * 64 + lane;
  const int c1 = 256 + c0;
  const u16* gA0 = Ab + (long long)(bm * 128 + (c0 >> 2)) * lda + (c0 & 3) * 8;
  const u16* gA1 = Ab + (long long)(bm * 128 + (c1 >> 2)) * lda + (c1 & 3) * 8;
  const u16* gB0 = Bb + (long long)(bn * 128 + (c0 >> 2)) * ldb + (c0 & 3) * 8;
  const u16* gB1 = Bb + (long long)(bn * 128 + (c1 >> 2)) * ldb + (c1 & 3) * 8;
  u16* lA0 = &lA[(wave * 64) * 8];
  u16* lA1 = &lA[(256 + wave * 64) * 8];
  u16* lB0 = &lB[(wave * 64) * 8];
  u16* lB1 = &lB[(256 + wave * 64) * 8];

  const int wm = (wave & 1) * 64, wn = (wave >> 1) * 64;
  const int aoff = (wm + (lane & 15)) * 32 + (lane >> 4) * 8;
  const int boff = (wn + (lane & 15)) * 32 + (lane >> 4) * 8;

  f32x4 acc[4][4];
  #pragma unroll
  for (int i = 0; i < 4; i++)
    #pragma unroll
    for (int j = 0; j < 4; j++) acc[i][j] = f32x4{0.f, 0.f, 0.f, 0.f};

  for (int k0 = 0; k0 < K; k0 += 32) {
    load16_to_lds(gA0 + k0, lA0);
    load16_to_lds(gA1 + k0, lA1);
    load16_to_lds(gB0 + k0, lB0);
    load16_to_lds(gB1 + k0, lB1);
    __syncthreads();
    bf16x8 af[4], bfv[4];
    #pragma unroll
    for (int i = 0; i < 4; i++) af[i]  = *(const bf16x8*)&lA[aoff + i * 16 * 32];
    #pragma unroll
    for (int j = 0; j < 4; j++) bfv[j] = *(const bf16x8*)&lB[boff + j * 16 * 32];
    #pragma unroll
    for (int i = 0; i < 4; i++)
      #pragma unroll
      for (int j = 0; j < 4; j++)
        acc[i][j] = __builtin_amdgcn_mfma_f32_16x16x32_bf16(af[i], bfv[j], acc[i][j], 0, 0, 0);
    __syncthreads();
  }

  // C/D layout (m89-verified): col = lane&15, row = (lane>>4)*4 + reg
  const int quad = lane >> 4, lc = lane & 15;
  const int rowb = bm * 128 + wm + quad * 4;
  const int colb = bn * 128 + wn + lc;

  if (MODE == 0) {
    const int region = colb >> 10;           // 0:q  1:k  2:v (64-col span stays in-region)
    if (region == 0) {
      // q: n-major, relu+eps, bf16
      u16* q = (u16*)Cv;
      #pragma unroll
      for (int i = 0; i < 4; i++)
        #pragma unroll
        for (int j = 0; j < 4; j++) {
          const int col = colb + j * 16;
          #pragma unroll
          for (int r = 0; r < 4; r++) {
            const int row = rowb + i * 16 + r;
            q[(long long)row * ldc + col] = f2b(fmaxf(acc[i][j][r], 0.f) + EPS);
          }
        }
    } else {
      // k/v: transposed store dst[d][n], packed 4×u16 (n-contiguous) per lane
      const bool isk = (region == 1);
      const int b = rowb >> 12;              // batch (128-row tile within one batch)
      u16* dst = (isk ? kT : vT) + (long long)b * 1024 * 4096;
      const int nloc = rowb & 4095;          // includes quad*4
      #pragma unroll
      for (int j = 0; j < 4; j++) {
        const int d = colb + j * 16 - region * 1024;
        float s = 0.f;
        #pragma unroll
        for (int i = 0; i < 4; i++) {
          ushort4 pk;
          #pragma unroll
          for (int r = 0; r < 4; r++) {
            float v = acc[i][j][r];
            if (isk) { v = fmaxf(v, 0.f) + EPS; s += v; }
            (&pk.x)[r] = f2b(v);
          }
          *(ushort4*)(dst + (long long)d * 4096 + nloc + i * 16) = pk;
        }
        if (isk) {
          s += __shfl_xor(s, 16);            // reduce across the 4 quads
          s += __shfl_xor(s, 32);            // (lanes sharing lc, 64 n-rows total)
          if (quad == 0) atomicAdd(&ksum[b * 1024 + d], s);
        }
      }
    }
  } else {
    #pragma unroll
    for (int i = 0; i < 4; i++) {
      #pragma unroll
      for (int j = 0; j < 4; j++) {
        const int col = colb + j * 16;
        float bj = 0.f;
        if (MODE == 2) bj = bias[col];
        #pragma unroll
        for (int r = 0; r < 4; r++) {
          const int row = rowb + i * 16 + r;
          float v = acc[i][j][r];
          if (MODE == 1) {
            ((u16*)Cv + (long long)bz * sC)[(long long)row * ldc + col] = f2b(v);
          } else {
            float zz = zvec[(long long)bz * M + row];
            ((float*)Cv + (long long)bz * sC)[(long long)row * ldc + col] = v * zz + bj;
          }
        }
      }
    }
  }
}

// fp32 -> bf16 bulk convert (vectorized, grid-stride)
__global__ void cvt_f32_bf16(const float* __restrict__ s, u16* __restrict__ d, int n4) {
  int i = blockIdx.x * blockDim.x + threadIdx.x;
  int st = gridDim.x * blockDim.x;
  for (; i < n4; i += st) {
    float4 f = ((const float4*)s)[i];
    uint2 o;
    o.x = (unsigned)f2b(f.x) | ((unsigned)f2b(f.y) << 16);
    o.y = (unsigned)f2b(f.z) | ((unsigned)f2b(f.w) << 16);
    ((uint2*)d)[i] = o;
  }
}

__global__ void zero_f32(float* __restrict__ p, int n) {
  int i = blockIdx.x * blockDim.x + threadIdx.x;
  if (i < n) p[i] = 0.f;
}

// z[row] = 1/(q[row,:]·ksum[b,:] + eps); one wave per row; q is [32768][1024]
__global__ void z_kernel(const u16* __restrict__ qbuf, const float* __restrict__ ksum,
                         float* __restrict__ z) {
  const int row  = blockIdx.x * 4 + (threadIdx.x >> 6);   // 0..32767
  const int lane = threadIdx.x & 63;
  const int b = row >> 12;
  const uint4* q = (const uint4*)(qbuf + (long long)row * 1024);
  const float* ks = ksum + b * 1024;
  float s = 0.f;
  #pragma unroll
  for (int c = 0; c < 2; c++) {
    int idx = lane + c * 64;
    uint4 d = q[idx];
    unsigned w[4] = {d.x, d.y, d.z, d.w};
    const float* kk = ks + idx * 8;
    #pragma unroll
    for (int qq = 0; qq < 4; qq++)
      s += b2f((u16)(w[qq] & 0xFFFF)) * kk[qq * 2]
         + b2f((u16)(w[qq] >> 16))    * kk[qq * 2 + 1];
  }
  #pragma unroll
  for (int o = 32; o > 0; o >>= 1) s += __shfl_down(s, o);
  if (lane == 0) z[row] = 1.0f / (s + EPS);
}

extern "C" void kernel_launch(void* const* d_in, const int* in_sizes, int n_in,
                              void* d_out, int out_size, void* d_ws, size_t ws_size,
                              hipStream_t stream) {
  const float* x    = (const float*)d_in[0];   // [8,4096,1024]
  const float* Wqkv = (const float*)d_in[1];   // [3072,1024]
  const float* Wout = (const float*)d_in[2];   // [1024,1024]
  const float* bout = (const float*)d_in[3];   // [1024]

  char* ws = (char*)d_ws;                      // ~310.6 MiB
  u16* x_bf    = (u16*)(ws + 0);               // 64 MiB
  u16* qbuf    = (u16*)(ws + 67108864);        // 64 MiB [32768][1024]
  u16* kT      = (u16*)(ws + 134217728);       // 64 MiB [8][1024][4096]
  u16* vT      = (u16*)(ws + 201326592);       // 64 MiB [8][1024][4096]
  u16* wqkv_bf = (u16*)(ws + 268435456);       // 6 MiB
  u16* wout_bf = (u16*)(ws + 274726912);       // 2 MiB
  u16* kv      = (u16*)(ws + 276824064);       // 16 MiB [8][1024][1024]
  u16* kvwT    = (u16*)(ws + 293601280);       // 16 MiB [8][1024][1024]
  float* ksum  = (float*)(ws + 310378496);     // 32 KiB [8][1024]
  float* z     = (float*)(ws + 310411264);     // 128 KiB [32768]

  // fp32 -> bf16 + ksum zero-init (ws is re-poisoned before every launch)
  cvt_f32_bf16<<<4096, 256, 0, stream>>>(x,    x_bf,    33554432 / 4);
  cvt_f32_bf16<<<1024, 256, 0, stream>>>(Wqkv, wqkv_bf,  3145728 / 4);
  cvt_f32_bf16<<<512,  256, 0, stream>>>(Wout, wout_bf,  1048576 / 4);
  zero_f32<<<32, 256, 0, stream>>>(ksum, 8192);

  // GEMM1: x @ Wqkv^T -> q (n-major) + kT/vT (transposed) + ksum
  gemm_abT<0><<<dim3(256, 24, 1), 256, 0, stream>>>(
      x_bf, wqkv_bf, qbuf, 32768, 3072, 1024, 1024, 1024, 1024,
      0, 0, 0, nullptr, nullptr, kT, vT, ksum);

  // z = 1/(q·ksum + eps)
  z_kernel<<<8192, 256, 0, stream>>>(qbuf, ksum, z);

  // GEMM2 (batched 8): kv[d][e] = kT_b @ vT_b^T  (K=4096)
  gemm_abT<1><<<dim3(8, 8, 8), 256, 0, stream>>>(
      kT, vT, kv, 1024, 1024, 4096, 4096, 4096, 1024,
      4194304, 4194304, 1048576, nullptr, nullptr, nullptr, nullptr, nullptr);

  // GEMM2b (batched 8): kvwT[f][d] = Wout @ kv_b^T  (K=1024)
  gemm_abT<1><<<dim3(8, 8, 8), 256, 0, stream>>>(
      wout_bf, kv, kvwT, 1024, 1024, 1024, 1024, 1024, 1024,
      0, 1048576, 1048576, nullptr, nullptr, nullptr, nullptr, nullptr);

  // GEMM3 (batched 8): out[n][f] = z[n] * (q_b @ kvwT_b^T) + b_out[f], fp32
  gemm_abT<2><<<dim3(32, 8, 8), 256, 0, stream>>>(
      qbuf, kvwT, d_out, 4096, 1024, 1024, 1024, 1024, 1024,
      4194304, 1048576, 4194304, z, bout, nullptr, nullptr, nullptr);
}